// Round 1
// baseline (153.765 us; speedup 1.0000x reference)
//
#include <hip/hip_runtime.h>

#define NN 4096
#define DD 512
#define CC 100

// ws layout (float indices)
#define G_OFF    0          // [CC][DD]  class-summed normalized image rows
#define CNT_OFF  51200      // [CC]      class counts (as float)
#define D_OFF    51328      // [NN]      d_i = <imgN_i, txtN_i>
#define INVT_OFF 55424      // [NN]      1/||txt_i||
#define NEG_OFF  59520      // [1]       global neg accumulator
#define WS_FLOATS 59524

// K1: per-row normalization, pos-dot, and atomic accumulation of G[label] += imgN_row.
// One block (128 threads) per row; each thread owns one float4 (128*4 = 512 = D).
__global__ __launch_bounds__(128) void k1_rows(const float* __restrict__ img,
                                               const float* __restrict__ txt,
                                               const int* __restrict__ labels,
                                               float* __restrict__ ws) {
    int row = blockIdx.x;
    int t   = threadIdx.x;
    float4 iv = ((const float4*)(img + (size_t)row * DD))[t];
    float4 tv = ((const float4*)(txt + (size_t)row * DD))[t];
    float ssi = iv.x*iv.x + iv.y*iv.y + iv.z*iv.z + iv.w*iv.w;
    float sst = tv.x*tv.x + tv.y*tv.y + tv.z*tv.z + tv.w*tv.w;
    float dot = iv.x*tv.x + iv.y*tv.y + iv.z*tv.z + iv.w*tv.w;
    #pragma unroll
    for (int o = 32; o >= 1; o >>= 1) {
        ssi += __shfl_xor(ssi, o);
        sst += __shfl_xor(sst, o);
        dot += __shfl_xor(dot, o);
    }
    __shared__ float s[6];
    if ((t & 63) == 0) { int w = t >> 6; s[w] = ssi; s[2+w] = sst; s[4+w] = dot; }
    __syncthreads();
    float inv_i = rsqrtf(s[0] + s[1]);
    float inv_t = rsqrtf(s[2] + s[3]);
    int lab = labels[row];
    if (t == 0) {
        ws[D_OFF + row]    = (s[4] + s[5]) * inv_i * inv_t;
        ws[INVT_OFF + row] = inv_t;
        atomicAdd(&ws[CNT_OFF + lab], 1.0f);
    }
    float* Gc = ws + G_OFF + (size_t)lab * DD + t * 4;
    atomicAdd(Gc + 0, iv.x * inv_i);
    atomicAdd(Gc + 1, iv.y * inv_i);
    atomicAdd(Gc + 2, iv.z * inv_i);
    atomicAdd(Gc + 3, iv.w * inv_i);
}

// K2: per-block 16 rows. R[i][c] = <txtN_i, G[c]>, S_i = sum_c R, then
// partial neg = sum cnt[c]*exp(S_i - R[i][c]); one atomicAdd per block.
#define ROWS 16
__global__ __launch_bounds__(256) void k2_neg(const float* __restrict__ txt,
                                              float* __restrict__ ws) {
    __shared__ float txts[ROWS][DD + 1];   // +1 pad: banks (r+k)%32, conflict-free broadcast
    __shared__ float cnts[CC];
    __shared__ float part[16][ROWS];
    __shared__ float Ss[ROWS];
    __shared__ float wred[4];
    int t  = threadIdx.x;
    int i0 = blockIdx.x * ROWS;
    if (t < CC) cnts[t] = ws[CNT_OFF + t];
    for (int idx = t; idx < ROWS * (DD/4); idx += 256) {
        int r  = idx >> 7;
        int c4 = idx & 127;
        float4 v  = ((const float4*)(txt + (size_t)(i0 + r) * DD))[c4];
        float inv = ws[INVT_OFF + i0 + r];
        txts[r][c4*4+0] = v.x * inv;
        txts[r][c4*4+1] = v.y * inv;
        txts[r][c4*4+2] = v.z * inv;
        txts[r][c4*4+3] = v.w * inv;
    }
    __syncthreads();
    int r = t & 15, g = t >> 4;       // 16 rows x 16 class-groups
    int c6 = (g < 4) ? (96 + g) : g;  // tail classes 96..99 live on groups 0..3
    float acc[7];
    #pragma unroll
    for (int j = 0; j < 7; j++) acc[j] = 0.f;
    const float* G = ws + G_OFF;
    for (int k = 0; k < DD; k++) {
        float tv = txts[r][k];
        #pragma unroll
        for (int j = 0; j < 6; j++)
            acc[j] += tv * G[(g + j*16) * DD + k];
        acc[6] += tv * G[c6 * DD + k];
    }
    float psum = acc[0]+acc[1]+acc[2]+acc[3]+acc[4]+acc[5] + ((g < 4) ? acc[6] : 0.f);
    part[g][r] = psum;
    __syncthreads();
    if (t < ROWS) {
        float ssum = 0.f;
        #pragma unroll
        for (int gg = 0; gg < 16; gg++) ssum += part[gg][t];
        Ss[t] = ssum;
    }
    __syncthreads();
    float S = Ss[r];
    float p = 0.f;
    #pragma unroll
    for (int j = 0; j < 6; j++) p += cnts[g + j*16] * __expf(S - acc[j]);
    if (g < 4) p += cnts[96 + g] * __expf(S - acc[6]);
    #pragma unroll
    for (int o = 32; o >= 1; o >>= 1) p += __shfl_xor(p, o);
    if ((t & 63) == 0) wred[t >> 6] = p;
    __syncthreads();
    if (t == 0) atomicAdd(&ws[NEG_OFF], wred[0]+wred[1]+wred[2]+wred[3]);
}

// K3: loss = sum_i [log(exp(d_i) + neg) - d_i]
__global__ __launch_bounds__(256) void k3_fin(const float* __restrict__ ws,
                                              float* __restrict__ out) {
    float neg = ws[NEG_OFF];
    int t = threadIdx.x;
    float s = 0.f;
    for (int i = t; i < NN; i += 256) {
        float dv = ws[D_OFF + i];
        s += logf(__expf(dv) + neg) - dv;
    }
    #pragma unroll
    for (int o = 32; o >= 1; o >>= 1) s += __shfl_xor(s, o);
    __shared__ float wred[4];
    if ((t & 63) == 0) wred[t >> 6] = s;
    __syncthreads();
    if (t == 0) out[0] = wred[0] + wred[1] + wred[2] + wred[3];
}

extern "C" void kernel_launch(void* const* d_in, const int* in_sizes, int n_in,
                              void* d_out, int out_size, void* d_ws, size_t ws_size,
                              hipStream_t stream) {
    const float* img   = (const float*)d_in[0];
    const float* txt   = (const float*)d_in[1];
    const int* labels  = (const int*)d_in[2];
    float* ws  = (float*)d_ws;
    float* out = (float*)d_out;

    hipMemsetAsync(d_ws, 0, WS_FLOATS * sizeof(float), stream);
    k1_rows<<<NN, 128, 0, stream>>>(img, txt, labels, ws);
    k2_neg<<<NN / ROWS, 256, 0, stream>>>(txt, ws);
    k3_fin<<<1, 256, 0, stream>>>(ws, out);
}

// Round 2
// 128.774 us; speedup vs baseline: 1.1941x; 1.1941x over previous
//
#include <hip/hip_runtime.h>

#define NN 4096
#define DD 512
#define CC 100
#define CP 128          // classes padded to 128 (pad rows: G=0, cnt=0 -> terms vanish)
#define BCAP 256        // bucket capacity per class (expected ~41, max ~65)

// ws word offsets
#define CNT_OFF    0        // int[CP]   class counts
#define NEG_OFF    128      // float     global neg accumulator
#define D_OFF      132      // float[NN] d_i = <imgN_i, txtN_i>
#define INVI_OFF   4228     // float[NN] 1/||img_i||
#define INVT_OFF   8324     // float[NN] 1/||txt_i||
#define BUCKET_OFF 12420    // int[CP*BCAP] row indices per class
#define G_OFF      45188    // float[CP][DD] class-summed normalized image rows
#define MEMSET_BYTES (132*4)  // only CNT + NEG need zeroing

// K1: per-row norms, pos-dot, bucket append. One 128-thread block per row.
__global__ __launch_bounds__(128) void k1_rows(const float* __restrict__ img,
                                               const float* __restrict__ txt,
                                               const int* __restrict__ labels,
                                               float* __restrict__ ws) {
    int row = blockIdx.x;
    int t   = threadIdx.x;
    float4 iv = ((const float4*)(img + (size_t)row * DD))[t];
    float4 tv = ((const float4*)(txt + (size_t)row * DD))[t];
    float ssi = iv.x*iv.x + iv.y*iv.y + iv.z*iv.z + iv.w*iv.w;
    float sst = tv.x*tv.x + tv.y*tv.y + tv.z*tv.z + tv.w*tv.w;
    float dot = iv.x*tv.x + iv.y*tv.y + iv.z*tv.z + iv.w*tv.w;
    #pragma unroll
    for (int o = 32; o >= 1; o >>= 1) {
        ssi += __shfl_xor(ssi, o);
        sst += __shfl_xor(sst, o);
        dot += __shfl_xor(dot, o);
    }
    __shared__ float s[6];
    if ((t & 63) == 0) { int w = t >> 6; s[w] = ssi; s[2+w] = sst; s[4+w] = dot; }
    __syncthreads();
    if (t == 0) {
        float inv_i = rsqrtf(s[0] + s[1]);
        float inv_t = rsqrtf(s[2] + s[3]);
        ws[D_OFF + row]    = (s[4] + s[5]) * inv_i * inv_t;
        ws[INVI_OFF + row] = inv_i;
        ws[INVT_OFF + row] = inv_t;
        int lab = labels[row];
        int* cnti   = (int*)ws;               // CNT_OFF = 0
        int* bucket = (int*)ws + BUCKET_OFF;
        int pos = atomicAdd(&cnti[lab], 1);
        if (pos > BCAP-1) pos = BCAP-1;       // safety clamp, never expected
        bucket[lab * BCAP + pos] = row;
    }
}

// K1b: one block per class; gather member rows (coalesced float4), no atomics.
__global__ __launch_bounds__(128) void k1b_gather(const float* __restrict__ img,
                                                  float* __restrict__ ws) {
    int c = blockIdx.x;
    int t = threadIdx.x;
    const int* cnti   = (const int*)ws;
    const int* bucket = (const int*)ws + BUCKET_OFF + c * BCAP;
    const float* invi = ws + INVI_OFF;
    const float4* img4 = (const float4*)img;
    int n = cnti[c];
    float ax = 0.f, ay = 0.f, az = 0.f, aw = 0.f;
    int s = 0;
    for (; s + 2 <= n; s += 2) {
        int j0 = bucket[s], j1 = bucket[s+1];
        float w0 = invi[j0], w1 = invi[j1];
        float4 v0 = img4[(size_t)j0 * 128 + t];
        float4 v1 = img4[(size_t)j1 * 128 + t];
        ax += v0.x*w0 + v1.x*w1;  ay += v0.y*w0 + v1.y*w1;
        az += v0.z*w0 + v1.z*w1;  aw += v0.w*w0 + v1.w*w1;
    }
    if (s < n) {
        int j0 = bucket[s];
        float w0 = invi[j0];
        float4 v0 = img4[(size_t)j0 * 128 + t];
        ax += v0.x*w0;  ay += v0.y*w0;  az += v0.z*w0;  aw += v0.w*w0;
    }
    float4 r; r.x = ax; r.y = ay; r.z = az; r.w = aw;
    ((float4*)(ws + G_OFF))[(size_t)c * 128 + t] = r;
}

// K2: 256 blocks x 16 rows. R[i][c] = <txtN_i, G[c]> via LDS-tiled vector GEMM,
// then neg partial = sum cnt[c]*exp(S_i - R[i][c]), one atomicAdd per block.
// LDS XOR-swizzle (word ^= 4*(row&7)) on both txts and gs -> conflict-free b128.
#define RB 16
#define NCH 16   // 512 / 32 k-floats per chunk
__global__ __launch_bounds__(256) void k2_neg(const float* __restrict__ txt,
                                              float* __restrict__ ws) {
    __shared__ float txts[RB * DD];     // 32 KB, swizzled
    __shared__ float gs[CP * 32];       // 16 KB, one k-chunk of G, swizzled
    __shared__ float cntf[CP];
    __shared__ float part[32][RB];
    __shared__ float Ss[RB];
    __shared__ float wred[4];
    int t  = threadIdx.x;
    int i0 = blockIdx.x * RB;
    const int* cnti = (const int*)ws;
    if (t < CP) cntf[t] = (float)cnti[t];

    // stage txtN rows (coalesced global read, swizzled conflict-free LDS write)
    const float4* txt4 = (const float4*)txt;
    for (int idx = t; idx < RB * 128; idx += 256) {
        int r = idx >> 7, k4 = idx & 127;
        float4 v = txt4[(size_t)(i0 + r) * 128 + k4];
        float w  = ws[INVT_OFF + i0 + r];
        v.x *= w; v.y *= w; v.z *= w; v.w *= w;
        *(float4*)&txts[r * DD + 4 * (k4 ^ (r & 7))] = v;
    }

    int r2 = t & 7;        // 8 row-slots: rows 2*r2, 2*r2+1
    int cg = t >> 3;       // 32 class-groups: classes cg + 32*j
    const float4* G4 = (const float4*)(ws + G_OFF);

    // per-thread staging coords: idx = t + 256*s -> (c, k4l)
    int sk0 = t & 7,          sc0 = t >> 3;
    int sk1 = (t+256) & 7,    sc1 = (t+256) >> 3;
    int sk2 = (t+512) & 7,    sc2 = (t+512) >> 3;
    int sk3 = (t+768) & 7,    sc3 = (t+768) >> 3;
    // prefetch chunk 0 into regs
    float4 p0 = G4[(size_t)sc0 * 128 + sk0];
    float4 p1 = G4[(size_t)sc1 * 128 + sk1];
    float4 p2 = G4[(size_t)sc2 * 128 + sk2];
    float4 p3 = G4[(size_t)sc3 * 128 + sk3];

    float acc[2][4] = {{0.f,0.f,0.f,0.f},{0.f,0.f,0.f,0.f}};
    int ra = 2 * r2, rb = 2 * r2 + 1;
    int sa = 4 * (ra & 7), sb = 4 * (rb & 7);   // txt swizzle bases (word^)

    for (int ch = 0; ch < NCH; ++ch) {
        __syncthreads();   // everyone done reading gs (and txts staged on ch=0)
        *(float4*)&gs[sc0*32 + 4*(sk0 ^ (sc0 & 7))] = p0;
        *(float4*)&gs[sc1*32 + 4*(sk1 ^ (sc1 & 7))] = p1;
        *(float4*)&gs[sc2*32 + 4*(sk2 ^ (sc2 & 7))] = p2;
        *(float4*)&gs[sc3*32 + 4*(sk3 ^ (sc3 & 7))] = p3;
        __syncthreads();   // gs ready
        if (ch + 1 < NCH) {  // issue next chunk's loads; they complete under compute
            int kb = (ch + 1) * 8;
            p0 = G4[(size_t)sc0 * 128 + kb + sk0];
            p1 = G4[(size_t)sc1 * 128 + kb + sk1];
            p2 = G4[(size_t)sc2 * 128 + kb + sk2];
            p3 = G4[(size_t)sc3 * 128 + kb + sk3];
        }
        #pragma unroll
        for (int k4l = 0; k4l < 8; ++k4l) {
            int kg4 = (ch * 8 + k4l) * 4;
            float4 t0 = *(const float4*)&txts[ra * DD + (kg4 ^ sa)];
            float4 t1 = *(const float4*)&txts[rb * DD + (kg4 ^ sb)];
            #pragma unroll
            for (int j = 0; j < 4; ++j) {
                int c = cg + 32 * j;
                float4 g = *(const float4*)&gs[c * 32 + 4 * (k4l ^ (c & 7))];
                acc[0][j] += t0.x*g.x + t0.y*g.y + t0.z*g.z + t0.w*g.w;
                acc[1][j] += t1.x*g.x + t1.y*g.y + t1.z*g.z + t1.w*g.w;
            }
        }
    }

    // per-row S = sum_c R[row][c]
    part[cg][ra] = acc[0][0] + acc[0][1] + acc[0][2] + acc[0][3];
    part[cg][rb] = acc[1][0] + acc[1][1] + acc[1][2] + acc[1][3];
    __syncthreads();
    if (t < RB) {
        float ssum = 0.f;
        #pragma unroll
        for (int g = 0; g < 32; ++g) ssum += part[g][t];
        Ss[t] = ssum;
    }
    __syncthreads();
    float S0 = Ss[ra], S1 = Ss[rb];
    float p = 0.f;
    #pragma unroll
    for (int j = 0; j < 4; ++j) {
        int c = cg + 32 * j;
        p += cntf[c] * (__expf(S0 - acc[0][j]) + __expf(S1 - acc[1][j]));
    }
    #pragma unroll
    for (int o = 32; o >= 1; o >>= 1) p += __shfl_xor(p, o);
    if ((t & 63) == 0) wred[t >> 6] = p;
    __syncthreads();
    if (t == 0) atomicAdd(ws + NEG_OFF, wred[0] + wred[1] + wred[2] + wred[3]);
}

// K3: loss = sum_i [log(exp(d_i) + neg) - d_i]
__global__ __launch_bounds__(256) void k3_fin(const float* __restrict__ ws,
                                              float* __restrict__ out) {
    float neg = ws[NEG_OFF];
    int t = threadIdx.x;
    float s = 0.f;
    for (int i = t; i < NN; i += 256) {
        float dv = ws[D_OFF + i];
        s += logf(__expf(dv) + neg) - dv;
    }
    #pragma unroll
    for (int o = 32; o >= 1; o >>= 1) s += __shfl_xor(s, o);
    __shared__ float wred[4];
    if ((t & 63) == 0) wred[t >> 6] = s;
    __syncthreads();
    if (t == 0) out[0] = wred[0] + wred[1] + wred[2] + wred[3];
}

extern "C" void kernel_launch(void* const* d_in, const int* in_sizes, int n_in,
                              void* d_out, int out_size, void* d_ws, size_t ws_size,
                              hipStream_t stream) {
    const float* img  = (const float*)d_in[0];
    const float* txt  = (const float*)d_in[1];
    const int* labels = (const int*)d_in[2];
    float* ws  = (float*)d_ws;
    float* out = (float*)d_out;

    hipMemsetAsync(d_ws, 0, MEMSET_BYTES, stream);
    k1_rows<<<NN, 128, 0, stream>>>(img, txt, labels, ws);
    k1b_gather<<<CP, 128, 0, stream>>>(img, ws);
    k2_neg<<<NN / RB, 256, 0, stream>>>(txt, ws);
    k3_fin<<<1, 256, 0, stream>>>(ws, out);
}

// Round 3
// 126.313 us; speedup vs baseline: 1.2173x; 1.0195x over previous
//
#include <hip/hip_runtime.h>

#define NN 4096
#define DD 512
#define CP 128          // classes padded to 128 (pad classes: cnt=0, G=0 -> terms vanish)
#define NB2 256         // k2 grid (NN/16)

// ws float-word offsets
#define NEG_OFF   0                    // float  global neg accumulator
#define DONE_OFF  1                    // int    done-block counter
#define D_OFF     64                   // float[NN] d_i = <imgN_i, txtN_i>
#define INVI_OFF  (64 + NN)            // float[NN] 1/||img_i||
#define INVT_OFF  (64 + 2*NN)          // float[NN] 1/||txt_i||
#define CNTF_OFF  (64 + 3*NN)          // float[CP] class counts
#define G_OFF     (64 + 3*NN + CP)     // float[CP][DD], 16B-aligned (12480*4 bytes)

// K1: wave-per-row norms + pos-dot. 1024 blocks x 256 (4 rows/block). No atomics.
__global__ __launch_bounds__(256) void k1_rows(const float* __restrict__ img,
                                               const float* __restrict__ txt,
                                               float* __restrict__ ws) {
    int w    = threadIdx.x >> 6;
    int lane = threadIdx.x & 63;
    int row  = blockIdx.x * 4 + w;
    const float4* i4 = (const float4*)(img + (size_t)row * DD);
    const float4* t4 = (const float4*)(txt + (size_t)row * DD);
    float4 a0 = i4[lane], a1 = i4[lane + 64];
    float4 b0 = t4[lane], b1 = t4[lane + 64];
    float ssi = a0.x*a0.x + a0.y*a0.y + a0.z*a0.z + a0.w*a0.w
              + a1.x*a1.x + a1.y*a1.y + a1.z*a1.z + a1.w*a1.w;
    float sst = b0.x*b0.x + b0.y*b0.y + b0.z*b0.z + b0.w*b0.w
              + b1.x*b1.x + b1.y*b1.y + b1.z*b1.z + b1.w*b1.w;
    float dot = a0.x*b0.x + a0.y*b0.y + a0.z*b0.z + a0.w*b0.w
              + a1.x*b1.x + a1.y*b1.y + a1.z*b1.z + a1.w*b1.w;
    #pragma unroll
    for (int o = 32; o >= 1; o >>= 1) {
        ssi += __shfl_xor(ssi, o);
        sst += __shfl_xor(sst, o);
        dot += __shfl_xor(dot, o);
    }
    if (lane == 0) {
        float inv_i = rsqrtf(ssi);
        float inv_t = rsqrtf(sst);
        ws[D_OFF + row]    = dot * inv_i * inv_t;
        ws[INVI_OFF + row] = inv_i;
        ws[INVT_OFF + row] = inv_t;
    }
    if (blockIdx.x == 0 && threadIdx.x == 0) {
        ws[NEG_OFF] = 0.0f;
        ((int*)ws)[DONE_OFF] = 0;
    }
}

// K1b: one block per class. Wave 0 scans labels via ballot/prefix-popcount (no
// atomics); then 4 groups of 128 threads gather member rows in parallel and
// combine in LDS. Writes G[c] and cntf[c].
__global__ __launch_bounds__(512) void k1b_gather(const float* __restrict__ img,
                                                  const int* __restrict__ labels,
                                                  float* __restrict__ ws) {
    __shared__ int list[256];
    __shared__ int scnt;
    __shared__ float4 pg[4][128];
    int c = blockIdx.x;
    int t = threadIdx.x;
    if (t < 64) {   // wave 0 fully active here
        int cnt = 0;
        for (int i = 0; i < NN / 64; ++i) {
            int lab = labels[i * 64 + t];
            unsigned long long m = __ballot(lab == c);
            int pre = (int)__popcll(m & ((1ull << t) - 1ull));
            if (lab == c) {
                int p = cnt + pre;
                if (p < 256) list[p] = i * 64 + t;
            }
            cnt += (int)__popcll(m);
        }
        if (t == 0) scnt = cnt < 256 ? cnt : 256;
    }
    __syncthreads();
    int n   = scnt;
    int sub = t >> 7;
    int l   = t & 127;
    const float* invi  = ws + INVI_OFF;
    const float4* img4 = (const float4*)img;
    float ax = 0.f, ay = 0.f, az = 0.f, aw = 0.f;
    for (int s = sub; s < n; s += 4) {
        int j = list[s];
        float wv = invi[j];
        float4 v = img4[(size_t)j * 128 + l];
        ax += v.x * wv; ay += v.y * wv; az += v.z * wv; aw += v.w * wv;
    }
    float4 mine; mine.x = ax; mine.y = ay; mine.z = az; mine.w = aw;
    pg[sub][l] = mine;
    __syncthreads();
    if (sub == 0) {
        float4 r0 = pg[0][l], r1 = pg[1][l], r2 = pg[2][l], r3 = pg[3][l];
        float4 r;
        r.x = r0.x + r1.x + r2.x + r3.x;
        r.y = r0.y + r1.y + r2.y + r3.y;
        r.z = r0.z + r1.z + r2.z + r3.z;
        r.w = r0.w + r1.w + r2.w + r3.w;
        ((float4*)(ws + G_OFF))[(size_t)c * 128 + l] = r;
        if (l == 0) ws[CNTF_OFF + c] = (float)n;
    }
}

// K2: 256 blocks x 16 rows. R[i][c] = <txtN_i, G[c]> via LDS-tiled vector GEMM,
// neg partial per block -> atomicAdd; LAST block (done-counter) computes the
// final loss sum over d_i and writes out[0]. LDS XOR-swizzled, conflict-free.
#define RB 16
#define NCH 16   // 512 / 32 k-floats per chunk
__global__ __launch_bounds__(256) void k2_neg(const float* __restrict__ txt,
                                              float* __restrict__ ws,
                                              float* __restrict__ out) {
    __shared__ float txts[RB * DD];     // 32 KB, swizzled
    __shared__ float gs[CP * 32];       // 16 KB, one k-chunk of G, swizzled
    __shared__ float cntf[CP];
    __shared__ float part[32][RB];
    __shared__ float Ss[RB];
    __shared__ float wred[4];
    __shared__ float sneg;
    __shared__ int   sdone;
    int t  = threadIdx.x;
    int i0 = blockIdx.x * RB;
    if (t < CP) cntf[t] = ws[CNTF_OFF + t];

    // stage txtN rows (coalesced global read, swizzled conflict-free LDS write)
    const float4* txt4 = (const float4*)txt;
    for (int idx = t; idx < RB * 128; idx += 256) {
        int r = idx >> 7, k4 = idx & 127;
        float4 v = txt4[(size_t)(i0 + r) * 128 + k4];
        float w  = ws[INVT_OFF + i0 + r];
        v.x *= w; v.y *= w; v.z *= w; v.w *= w;
        *(float4*)&txts[r * DD + 4 * (k4 ^ (r & 7))] = v;
    }

    int r2 = t & 7;        // 8 row-slots: rows 2*r2, 2*r2+1
    int cg = t >> 3;       // 32 class-groups: classes cg + 32*j
    const float4* G4 = (const float4*)(ws + G_OFF);

    // per-thread staging coords: idx = t + 256*s -> (c, k4l)
    int sk0 = t & 7,          sc0 = t >> 3;
    int sk1 = (t+256) & 7,    sc1 = (t+256) >> 3;
    int sk2 = (t+512) & 7,    sc2 = (t+512) >> 3;
    int sk3 = (t+768) & 7,    sc3 = (t+768) >> 3;
    // prefetch chunk 0 into regs
    float4 p0 = G4[(size_t)sc0 * 128 + sk0];
    float4 p1 = G4[(size_t)sc1 * 128 + sk1];
    float4 p2 = G4[(size_t)sc2 * 128 + sk2];
    float4 p3 = G4[(size_t)sc3 * 128 + sk3];

    float acc[2][4] = {{0.f,0.f,0.f,0.f},{0.f,0.f,0.f,0.f}};
    int ra = 2 * r2, rb = 2 * r2 + 1;
    int sa = 4 * (ra & 7), sb = 4 * (rb & 7);   // txt swizzle bases (word^)

    for (int ch = 0; ch < NCH; ++ch) {
        __syncthreads();   // everyone done reading gs (and txts staged on ch=0)
        *(float4*)&gs[sc0*32 + 4*(sk0 ^ (sc0 & 7))] = p0;
        *(float4*)&gs[sc1*32 + 4*(sk1 ^ (sc1 & 7))] = p1;
        *(float4*)&gs[sc2*32 + 4*(sk2 ^ (sc2 & 7))] = p2;
        *(float4*)&gs[sc3*32 + 4*(sk3 ^ (sc3 & 7))] = p3;
        __syncthreads();   // gs ready
        if (ch + 1 < NCH) {  // issue next chunk's loads; complete under compute
            int kb = (ch + 1) * 8;
            p0 = G4[(size_t)sc0 * 128 + kb + sk0];
            p1 = G4[(size_t)sc1 * 128 + kb + sk1];
            p2 = G4[(size_t)sc2 * 128 + kb + sk2];
            p3 = G4[(size_t)sc3 * 128 + kb + sk3];
        }
        #pragma unroll
        for (int k4l = 0; k4l < 8; ++k4l) {
            int kg4 = (ch * 8 + k4l) * 4;
            float4 t0 = *(const float4*)&txts[ra * DD + (kg4 ^ sa)];
            float4 t1 = *(const float4*)&txts[rb * DD + (kg4 ^ sb)];
            #pragma unroll
            for (int j = 0; j < 4; ++j) {
                int c = cg + 32 * j;
                float4 g = *(const float4*)&gs[c * 32 + 4 * (k4l ^ (c & 7))];
                acc[0][j] += t0.x*g.x + t0.y*g.y + t0.z*g.z + t0.w*g.w;
                acc[1][j] += t1.x*g.x + t1.y*g.y + t1.z*g.z + t1.w*g.w;
            }
        }
    }

    // per-row S = sum_c R[row][c]
    part[cg][ra] = acc[0][0] + acc[0][1] + acc[0][2] + acc[0][3];
    part[cg][rb] = acc[1][0] + acc[1][1] + acc[1][2] + acc[1][3];
    __syncthreads();
    if (t < RB) {
        float ssum = 0.f;
        #pragma unroll
        for (int g = 0; g < 32; ++g) ssum += part[g][t];
        Ss[t] = ssum;
    }
    __syncthreads();
    float S0 = Ss[ra], S1 = Ss[rb];
    float p = 0.f;
    #pragma unroll
    for (int j = 0; j < 4; ++j) {
        int c = cg + 32 * j;
        p += cntf[c] * (__expf(S0 - acc[0][j]) + __expf(S1 - acc[1][j]));
    }
    #pragma unroll
    for (int o = 32; o >= 1; o >>= 1) p += __shfl_xor(p, o);
    if ((t & 63) == 0) wred[t >> 6] = p;
    __syncthreads();
    if (t == 0) {
        atomicAdd(ws + NEG_OFF, wred[0] + wred[1] + wred[2] + wred[3]);
        __threadfence();
        int old = atomicAdd((int*)ws + DONE_OFF, 1);
        sdone = (old == NB2 - 1);
        if (sdone) sneg = atomicAdd(ws + NEG_OFF, 0.0f);  // coherent read-back
    }
    __syncthreads();
    if (sdone) {
        // fused finalize: loss = sum_i [log(exp(d_i) + neg) - d_i]
        float neg = sneg;
        float s = 0.f;
        for (int i = t; i < NN; i += 256) {
            float dv = ws[D_OFF + i];
            s += logf(__expf(dv) + neg) - dv;
        }
        #pragma unroll
        for (int o = 32; o >= 1; o >>= 1) s += __shfl_xor(s, o);
        __syncthreads();                  // wred reuse safe
        if ((t & 63) == 0) wred[t >> 6] = s;
        __syncthreads();
        if (t == 0) out[0] = wred[0] + wred[1] + wred[2] + wred[3];
    }
}

extern "C" void kernel_launch(void* const* d_in, const int* in_sizes, int n_in,
                              void* d_out, int out_size, void* d_ws, size_t ws_size,
                              hipStream_t stream) {
    const float* img  = (const float*)d_in[0];
    const float* txt  = (const float*)d_in[1];
    const int* labels = (const int*)d_in[2];
    float* ws  = (float*)d_ws;
    float* out = (float*)d_out;

    k1_rows<<<NN / 4, 256, 0, stream>>>(img, txt, ws);
    k1b_gather<<<CP, 512, 0, stream>>>(img, labels, ws);
    k2_neg<<<NB2, 256, 0, stream>>>(txt, ws, out);
}

// Round 5
// 104.847 us; speedup vs baseline: 1.4666x; 1.2047x over previous
//
#include <hip/hip_runtime.h>

#define NN 4096
#define DD 512
#define CP 128          // classes padded to 128 (pad classes: cnt=0, G=0 -> vanish)
#define MT 64           // k2 M-tile rows per block
#define NB2 (NN / MT)   // 64 blocks

// ws float-word offsets
#define NEG_OFF   0
#define DONE_OFF  1
#define D_OFF     64
#define INVI_OFF  (64 + NN)
#define INVT_OFF  (64 + 2*NN)
#define CNTF_OFF  (64 + 3*NN)
#define TXB_OFF_W 16384                      // bf16 txtN [NN][DD] starts here
#define GB_OFF_W  (TXB_OFF_W + NN*DD/2)      // bf16 G [CP][DD]

typedef __attribute__((ext_vector_type(8))) short bf16x8;
typedef __attribute__((ext_vector_type(4))) float f32x4;

static __device__ inline unsigned short f2bf(float f) {
    unsigned int u = __float_as_uint(f);
    unsigned int r = u + 0x7fffu + ((u >> 16) & 1u);   // round-to-nearest-even
    return (unsigned short)(r >> 16);
}

// K1: wave-per-row norms + pos-dot; writes txtN as bf16. No atomics.
__global__ __launch_bounds__(256) void k1_rows(const float* __restrict__ img,
                                               const float* __restrict__ txt,
                                               float* __restrict__ ws) {
    int w = threadIdx.x >> 6, l = threadIdx.x & 63;
    int row = blockIdx.x * 4 + w;
    const float4* i4 = (const float4*)(img + (size_t)row * DD);
    const float4* t4 = (const float4*)(txt + (size_t)row * DD);
    float4 a0 = i4[l], a1 = i4[l + 64];
    float4 b0 = t4[l], b1 = t4[l + 64];
    float ssi = a0.x*a0.x + a0.y*a0.y + a0.z*a0.z + a0.w*a0.w
              + a1.x*a1.x + a1.y*a1.y + a1.z*a1.z + a1.w*a1.w;
    float sst = b0.x*b0.x + b0.y*b0.y + b0.z*b0.z + b0.w*b0.w
              + b1.x*b1.x + b1.y*b1.y + b1.z*b1.z + b1.w*b1.w;
    float dot = a0.x*b0.x + a0.y*b0.y + a0.z*b0.z + a0.w*b0.w
              + a1.x*b1.x + a1.y*b1.y + a1.z*b1.z + a1.w*b1.w;
    #pragma unroll
    for (int o = 32; o >= 1; o >>= 1) {
        ssi += __shfl_xor(ssi, o);
        sst += __shfl_xor(sst, o);
        dot += __shfl_xor(dot, o);
    }
    float inv_t = rsqrtf(sst);
    unsigned short* txb = (unsigned short*)(ws + TXB_OFF_W);
    ushort4 s0, s1;
    s0.x = f2bf(b0.x * inv_t); s0.y = f2bf(b0.y * inv_t);
    s0.z = f2bf(b0.z * inv_t); s0.w = f2bf(b0.w * inv_t);
    s1.x = f2bf(b1.x * inv_t); s1.y = f2bf(b1.y * inv_t);
    s1.z = f2bf(b1.z * inv_t); s1.w = f2bf(b1.w * inv_t);
    *(ushort4*)(txb + (size_t)row * DD + 4 * l)       = s0;
    *(ushort4*)(txb + (size_t)row * DD + 256 + 4 * l) = s1;
    if (l == 0) {
        float inv_i = rsqrtf(ssi);
        ws[D_OFF + row]    = dot * inv_i * inv_t;
        ws[INVI_OFF + row] = inv_i;
        ws[INVT_OFF + row] = inv_t;
    }
    if (blockIdx.x == 0 && threadIdx.x == 0) {
        ws[NEG_OFF] = 0.0f;
        ((int*)ws)[DONE_OFF] = 0;
    }
}

// K1b: one block per class; ballot-scan labels, gather member rows, write G bf16.
__global__ __launch_bounds__(512) void k1b_gather(const float* __restrict__ img,
                                                  const int* __restrict__ labels,
                                                  float* __restrict__ ws) {
    __shared__ int list[256];
    __shared__ int scnt;
    __shared__ float4 pg[4][128];
    int c = blockIdx.x;
    int t = threadIdx.x;
    if (t < 64) {   // wave 0 fully active
        int cnt = 0;
        for (int i = 0; i < NN / 64; ++i) {
            int lab = labels[i * 64 + t];
            unsigned long long m = __ballot(lab == c);
            int pre = (int)__popcll(m & ((1ull << t) - 1ull));
            if (lab == c) {
                int p = cnt + pre;
                if (p < 256) list[p] = i * 64 + t;
            }
            cnt += (int)__popcll(m);
        }
        if (t == 0) scnt = cnt < 256 ? cnt : 256;
    }
    __syncthreads();
    int n   = scnt;
    int sub = t >> 7;
    int l   = t & 127;
    const float* invi  = ws + INVI_OFF;
    const float4* img4 = (const float4*)img;
    float ax = 0.f, ay = 0.f, az = 0.f, aw = 0.f;
    for (int s = sub; s < n; s += 4) {
        int j = list[s];
        float wv = invi[j];
        float4 v = img4[(size_t)j * 128 + l];
        ax += v.x * wv; ay += v.y * wv; az += v.z * wv; aw += v.w * wv;
    }
    float4 mine; mine.x = ax; mine.y = ay; mine.z = az; mine.w = aw;
    pg[sub][l] = mine;
    __syncthreads();
    if (sub == 0) {
        float4 r0 = pg[0][l], r1 = pg[1][l], r2 = pg[2][l], r3 = pg[3][l];
        float rx = r0.x + r1.x + r2.x + r3.x;
        float ry = r0.y + r1.y + r2.y + r3.y;
        float rz = r0.z + r1.z + r2.z + r3.z;
        float rw = r0.w + r1.w + r2.w + r3.w;
        unsigned short* gbf = (unsigned short*)(ws + GB_OFF_W);
        ushort4 o;
        o.x = f2bf(rx); o.y = f2bf(ry); o.z = f2bf(rz); o.w = f2bf(rw);
        *(ushort4*)(gbf + (size_t)c * DD + 4 * l) = o;
        if (l == 0) ws[CNTF_OFF + c] = (float)n;
    }
}

// K2: MFMA GEMM R[4096x128] = txtN_bf16 @ G_bf16^T, fused exp/neg epilogue,
// done-counter finalize. 64 blocks x 4 waves; tile M=64,N=128,K-chunk=32.
__global__ __launch_bounds__(256) void k2_neg(float* __restrict__ ws,
                                              float* __restrict__ out) {
    __shared__ __align__(16) unsigned short As[2][MT * 32];   // 4KB per buf
    __shared__ __align__(16) unsigned short Bs[2][CP * 32];   // 8KB per buf
    __shared__ float cnts[CP];
    __shared__ float wred[4];
    __shared__ float sneg;
    __shared__ int   sdone;
    int t = threadIdx.x;
    int w = t >> 6, l = t & 63;
    int row0 = blockIdx.x * MT;
    if (t < CP) cnts[t] = ws[CNTF_OFF + t];
    const unsigned short* txb = (const unsigned short*)(ws + TXB_OFF_W);
    const unsigned short* gbf = (const unsigned short*)(ws + GB_OFF_W);

    // staging coords: A: thread t -> (row t>>2, k-octet t&3); B: rows t>>2 and t>>2+64
    int arow = t >> 2, koct = t & 3;
    const int4* gA  = (const int4*)(txb + (size_t)(row0 + arow) * DD + koct * 8);
    const int4* gB0 = (const int4*)(gbf + (size_t)arow * DD + koct * 8);
    const int4* gB1 = (const int4*)(gbf + (size_t)(arow + 64) * DD + koct * 8);
    unsigned short* wA  = &As[0][arow * 32 + koct * 8];   // (+buf*MT*32)
    unsigned short* wB0 = &Bs[0][arow * 32 + koct * 8];
    unsigned short* wB1 = &Bs[0][(arow + 64) * 32 + koct * 8];

    f32x4 acc[8];
    f32x4 zero = {0.f, 0.f, 0.f, 0.f};
    #pragma unroll
    for (int f = 0; f < 8; ++f) acc[f] = zero;

    // prologue: stage chunk 0 into buf 0
    int4 ra = gA[0], rb0 = gB0[0], rb1 = gB1[0];
    *(int4*)wA = ra; *(int4*)wB0 = rb0; *(int4*)wB1 = rb1;
    __syncthreads();

    int afoff = (w * 16 + (l & 15)) * 32 + (l >> 4) * 8;
    int bfoff = (l & 15) * 32 + (l >> 4) * 8;

    for (int ch = 0; ch < 16; ++ch) {
        int cur = ch & 1;
        if (ch < 15) {   // issue next chunk's loads; complete under compute
            ra  = gA [(ch + 1) * 4];
            rb0 = gB0[(ch + 1) * 4];
            rb1 = gB1[(ch + 1) * 4];
        }
        bf16x8 af = *(const bf16x8*)&As[cur][afoff];
        #pragma unroll
        for (int f = 0; f < 8; ++f) {
            bf16x8 bfr = *(const bf16x8*)&Bs[cur][f * 16 * 32 + bfoff];
            acc[f] = __builtin_amdgcn_mfma_f32_16x16x32_bf16(af, bfr, acc[f], 0, 0, 0);
        }
        if (ch < 15) {
            int nxt = cur ^ 1;
            *(int4*)(wA  + nxt * MT * 32) = ra;
            *(int4*)(wB0 + nxt * CP * 32) = rb0;
            *(int4*)(wB1 + nxt * CP * 32) = rb1;
        }
        __syncthreads();
    }

    // epilogue: S per row (frag-sum + xor-reduce over col lanes), then exp terms
    float rs[4];
    #pragma unroll
    for (int r = 0; r < 4; ++r) {
        float s = 0.f;
        #pragma unroll
        for (int f = 0; f < 8; ++f) s += acc[f][r];
        #pragma unroll
        for (int o = 1; o < 16; o <<= 1) s += __shfl_xor(s, o);
        rs[r] = s;
    }
    float p = 0.f;
    #pragma unroll
    for (int f = 0; f < 8; ++f) {
        float cf = cnts[f * 16 + (l & 15)];
        float e = 0.f;
        #pragma unroll
        for (int r = 0; r < 4; ++r) e += __expf(rs[r] - acc[f][r]);
        p += cf * e;
    }
    #pragma unroll
    for (int o = 32; o >= 1; o >>= 1) p += __shfl_xor(p, o);
    if (l == 0) wred[w] = p;
    __syncthreads();
    if (t == 0) {
        atomicAdd(ws + NEG_OFF, wred[0] + wred[1] + wred[2] + wred[3]);
        __threadfence();
        int old = atomicAdd((int*)ws + DONE_OFF, 1);
        sdone = (old == NB2 - 1);
        if (sdone) sneg = atomicAdd(ws + NEG_OFF, 0.0f);  // coherent read-back
    }
    __syncthreads();
    if (sdone) {
        float neg = sneg;
        float s = 0.f;
        for (int i = t; i < NN; i += 256) {
            float dv = ws[D_OFF + i];
            s += logf(__expf(dv) + neg) - dv;
        }
        #pragma unroll
        for (int o = 32; o >= 1; o >>= 1) s += __shfl_xor(s, o);
        __syncthreads();
        if (l == 0) wred[w] = s;
        __syncthreads();
        if (t == 0) out[0] = wred[0] + wred[1] + wred[2] + wred[3];
    }
}

extern "C" void kernel_launch(void* const* d_in, const int* in_sizes, int n_in,
                              void* d_out, int out_size, void* d_ws, size_t ws_size,
                              hipStream_t stream) {
    const float* img  = (const float*)d_in[0];
    const float* txt  = (const float*)d_in[1];
    const int* labels = (const int*)d_in[2];
    float* ws  = (float*)d_ws;
    float* out = (float*)d_out;

    k1_rows<<<NN / 4, 256, 0, stream>>>(img, txt, ws);
    k1b_gather<<<CP, 512, 0, stream>>>(img, labels, ws);
    k2_neg<<<NB2, 256, 0, stream>>>(ws, out);
}